// Round 1
// baseline (566.052 us; speedup 1.0000x reference)
//
#include <hip/hip_runtime.h>

#define IH 128
#define IW 128
#define NPI (IH*IW)   // 16384 pixels per image
// B=2, HEADS=8, D=8, KK=9, ATTN_DIM=72, DIMS={18,36,72}, SD=126

// ---------- K0: transpose pw-conv weights for contiguous scalar loads ----------
// wT[dkk*144 + br*72 + c] = dc{br}_pw_w[c*72 + dkk]
__global__ __launch_bounds__(256) void k_wt(const float* __restrict__ w1,
                                            const float* __restrict__ w2,
                                            float* __restrict__ wT) {
  int i = blockIdx.x * 256 + threadIdx.x;
  if (i < 72 * 72) {
    int c = i / 72, dkk = i % 72;
    wT[dkk * 144 + c]      = w1[i];
    wT[dkk * 144 + 72 + c] = w2[i];
  }
}

// ---------- K1: qkv = x @ qkv_w + b, output planar f[(b*192+j)*NPI + p] ----------
__global__ __launch_bounds__(256) void k_qkv(const float* __restrict__ x,
                                             const float* __restrict__ w,
                                             const float* __restrict__ bias,
                                             float* __restrict__ f) {
  int t = threadIdx.x;
  int lane = t & 63;
  int wv = __builtin_amdgcn_readfirstlane(t >> 6);
  int gp = blockIdx.x * 64 + lane;      // global pixel 0..32767
  int b = gp >> 14;
  int pp = gp & (NPI - 1);
  const float* xrow = x + (size_t)gp * 256;
  int jbase = wv * 48;
  float acc[48];
#pragma unroll
  for (int jj = 0; jj < 48; ++jj) acc[jj] = bias[jbase + jj];
  for (int c = 0; c < 256; c += 8) {
    float xr[8];
#pragma unroll
    for (int q4 = 0; q4 < 2; ++q4) {
      float4 v = *reinterpret_cast<const float4*>(xrow + c + q4 * 4);
      xr[q4 * 4 + 0] = v.x; xr[q4 * 4 + 1] = v.y;
      xr[q4 * 4 + 2] = v.z; xr[q4 * 4 + 3] = v.w;
    }
#pragma unroll
    for (int jt = 0; jt < 48; jt += 4) {
#pragma unroll
      for (int cc = 0; cc < 8; ++cc) {
        const float* wp = w + (c + cc) * 192 + jbase + jt;  // wave-uniform -> s_load
        acc[jt + 0] += xr[cc] * wp[0];
        acc[jt + 1] += xr[cc] * wp[1];
        acc[jt + 2] += xr[cc] * wp[2];
        acc[jt + 3] += xr[cc] * wp[3];
      }
    }
  }
#pragma unroll
  for (int jj = 0; jj < 48; ++jj) {
    int j = jbase + jj;
    f[((size_t)(b * 192 + j)) * NPI + pp] = acc[jj];
  }
}

// ---------- K2/K8: dep() fused with consumer ----------
// MODE 0: k-path -> softmax -> attn1[(bh*9+kk)*NPI+p]
// MODE 1: v-path -> out[d] = sum_kk (gout+attn1)*v -> pre[(bh*8+d)*NPI+p]
template <int MODE>
__global__ __launch_bounds__(256) void k_dep(const float* __restrict__ f,
    const float* __restrict__ dwW1, const float* __restrict__ dwB1,
    const float* __restrict__ dwW2, const float* __restrict__ dwB2,
    const float* __restrict__ wT,  const float* __restrict__ pwB1,
    const float* __restrict__ pwB2, const float* __restrict__ rpb,
    const float* __restrict__ gout, const float* __restrict__ attn_in,
    float* __restrict__ outp) {
  __shared__ float kin[8][20][20];
  __shared__ float dwa[8][18][18];
  __shared__ float dwb[8][18][18];
  int t = threadIdx.x;
  int tile = blockIdx.x;
  int bh = blockIdx.y;
  int h = bh & 7;
  int y0 = (tile >> 3) << 4, x0 = (tile & 7) << 4;
  const float* src = f + ((size_t)(bh * 24 + (MODE ? 16 : 8))) * NPI;
  // stage k_in/v_in tile with halo 2 (zero padded)
  for (int idx = t; idx < 8 * 20 * 20; idx += 256) {
    int c = idx / 400, r = idx % 400, yy = r / 20, xx = r % 20;
    int ay = y0 - 2 + yy, ax = x0 - 2 + xx;
    float v = 0.f;
    if ((unsigned)ay < (unsigned)IH && (unsigned)ax < (unsigned)IW)
      v = src[c * NPI + ay * IW + ax];
    kin[c][yy][xx] = v;
  }
  __syncthreads();
  // depthwise 3x3, both branches; out-of-image positions are ZERO (pw-conv padding)
  for (int idx = t; idx < 8 * 18 * 18; idx += 256) {
    int c = idx / 324, r = idx % 324, yy = r / 18, xx = r % 18;
    int ay = y0 - 1 + yy, ax = x0 - 1 + xx;
    float va = 0.f, vb = 0.f;
    if ((unsigned)ay < (unsigned)IH && (unsigned)ax < (unsigned)IW) {
      va = dwB1[c]; vb = dwB2[c];
#pragma unroll
      for (int ky = 0; ky < 3; ++ky)
#pragma unroll
        for (int kx = 0; kx < 3; ++kx) {
          float s = kin[c][yy + ky][xx + kx];
          va += dwW1[c * 9 + ky * 3 + kx] * s;
          vb += dwW2[c * 9 + ky * 3 + kx] * s;
        }
    }
    dwa[c][yy][xx] = va;
    dwb[c][yy][xx] = vb;
  }
  __syncthreads();
  int ly = t >> 4, lx = t & 15;
  int p = (y0 + ly) * IW + (x0 + lx);
  float acc[72];
#pragma unroll
  for (int c = 0; c < 72; ++c) {
    acc[c] = pwB1[c] + pwB2[c];
    if (MODE == 0) acc[c] += rpb[h * 9 + (c % 9)];
  }
#pragma unroll 1
  for (int dkk = 0; dkk < 72; ++dkk) {
    int d = dkk / 9; int t9 = dkk - d * 9; int ky = t9 / 3; int kx = t9 - ky * 3;
    float v1 = dwa[d][ly + ky][lx + kx];
    float v2 = dwb[d][ly + ky][lx + kx];
    const float* wp = wT + dkk * 144;   // wave-uniform -> s_load batches
#pragma unroll
    for (int c = 0; c < 72; ++c) {
      acc[c] += wp[c] * v1;
      acc[c] += wp[72 + c] * v2;
    }
  }
  if (MODE == 0) {
    float q[8];
#pragma unroll
    for (int d = 0; d < 8; ++d) q[d] = f[((size_t)(bh * 24 + d)) * NPI + p];
    float e[9];
    float m = -1e30f;
#pragma unroll
    for (int kk = 0; kk < 9; ++kk) {
      float s = 0.f;
#pragma unroll
      for (int d = 0; d < 8; ++d) s += q[d] * acc[d * 9 + kk];
      e[kk] = s;
      m = fmaxf(m, s);
    }
    float sum = 0.f;
#pragma unroll
    for (int kk = 0; kk < 9; ++kk) { e[kk] = __expf(e[kk] - m); sum += e[kk]; }
    float r = 1.f / sum;
#pragma unroll
    for (int kk = 0; kk < 9; ++kk)
      outp[((size_t)(bh * 9 + kk)) * NPI + p] = e[kk] * r;
  } else {
    float coef[9];
#pragma unroll
    for (int kk = 0; kk < 9; ++kk)
      coef[kk] = gout[((size_t)(bh * 9 + kk)) * NPI + p] +
                 attn_in[((size_t)(bh * 9 + kk)) * NPI + p];
#pragma unroll
    for (int d = 0; d < 8; ++d) {
      float s = 0.f;
#pragma unroll
      for (int kk = 0; kk < 9; ++kk) s += coef[kk] * acc[d * 9 + kk];
      outp[((size_t)(bh * 8 + d)) * NPI + p] = s;
    }
  }
}

// ---------- K3: pin 1x1 conv 72->144 ----------
__global__ __launch_bounds__(256) void k_pin(const float* __restrict__ attn,
                                             const float* __restrict__ w,
                                             const float* __restrict__ bias,
                                             float* __restrict__ fused) {
  int t = threadIdx.x, lane = t & 63;
  int wv = __builtin_amdgcn_readfirstlane(t >> 6);
  int gp = blockIdx.x * 64 + lane;
  int b = gp >> 14, p = gp & (NPI - 1);
  const float* ap = attn + (size_t)b * 72 * NPI + p;
  float a[72];
#pragma unroll
  for (int i = 0; i < 72; ++i) a[i] = ap[i * NPI];
  int j0 = wv * 36;
#pragma unroll 1
  for (int jj = 0; jj < 36; ++jj) {
    int j = j0 + jj;
    const float* wp = w + j * 72;
    float s = bias[j];
#pragma unroll
    for (int i = 0; i < 72; ++i) s += wp[i] * a[i];
    fused[((size_t)b * 144 + j) * NPI + p] = s;
  }
}

// ---------- K4: fused depthwise 7x7 -> relu -> 5x5 -> relu -> 3x3 ----------
__global__ __launch_bounds__(256) void k_dwchain(const float* __restrict__ fused,
    const float* __restrict__ w7, const float* __restrict__ b7,
    const float* __restrict__ w5, const float* __restrict__ b5,
    const float* __restrict__ w3, const float* __restrict__ b3,
    float* __restrict__ dwout) {
  __shared__ float s_in[28][28];
  __shared__ float s_t7[22][22];
  __shared__ float s_t5[18][18];
  int t = threadIdx.x;
  int tile = blockIdx.x;
  int c = blockIdx.y;       // 0..125  (abc channel)
  int b = blockIdx.z;
  int y0 = (tile >> 3) << 4, x0 = (tile & 7) << 4;
  const float* src = fused + ((size_t)b * 144 + 18 + c) * NPI;
  for (int idx = t; idx < 28 * 28; idx += 256) {
    int yy = idx / 28, xx = idx % 28;
    int ay = y0 - 6 + yy, ax = x0 - 6 + xx;
    s_in[yy][xx] = ((unsigned)ay < (unsigned)IH && (unsigned)ax < (unsigned)IW)
                       ? src[ay * IW + ax] : 0.f;
  }
  __syncthreads();
  for (int idx = t; idx < 22 * 22; idx += 256) {
    int yy = idx / 22, xx = idx % 22;
    int ay = y0 - 3 + yy, ax = x0 - 3 + xx;
    float s = 0.f;
    if ((unsigned)ay < (unsigned)IH && (unsigned)ax < (unsigned)IW) {
      s = b7[c];
#pragma unroll
      for (int ky = 0; ky < 7; ++ky)
#pragma unroll
        for (int kx = 0; kx < 7; ++kx)
          s += w7[c * 49 + ky * 7 + kx] * s_in[yy + ky][xx + kx];
      s = fmaxf(s, 0.f);
    }
    s_t7[yy][xx] = s;
  }
  __syncthreads();
  for (int idx = t; idx < 18 * 18; idx += 256) {
    int yy = idx / 18, xx = idx % 18;
    int ay = y0 - 1 + yy, ax = x0 - 1 + xx;
    float s = 0.f;
    if ((unsigned)ay < (unsigned)IH && (unsigned)ax < (unsigned)IW) {
      s = b5[c];
#pragma unroll
      for (int ky = 0; ky < 5; ++ky)
#pragma unroll
        for (int kx = 0; kx < 5; ++kx)
          s += w5[c * 25 + ky * 5 + kx] * s_t7[yy + ky][xx + kx];
      s = fmaxf(s, 0.f);
    }
    s_t5[yy][xx] = s;
  }
  __syncthreads();
  int ly = t >> 4, lx = t & 15;
  float s = b3[c];
#pragma unroll
  for (int ky = 0; ky < 3; ++ky)
#pragma unroll
    for (int kx = 0; kx < 3; ++kx)
      s += w3[c * 9 + ky * 3 + kx] * s_t5[ly + ky][lx + kx];
  dwout[((size_t)b * 126 + c) * NPI + (y0 + ly) * IW + (x0 + lx)] = s;
}

// ---------- K5: g1 = pwa*d0 ; g2 = (pw1 g1 + b)*d1 ----------
__global__ __launch_bounds__(256) void k_g1(const float* __restrict__ fused,
                                            const float* __restrict__ dw,
                                            const float* __restrict__ w,
                                            const float* __restrict__ bias,
                                            float* __restrict__ g2) {
  int t = threadIdx.x, lane = t & 63;
  int wv = __builtin_amdgcn_readfirstlane(t >> 6);
  int gp = blockIdx.x * 64 + lane;
  int b = gp >> 14, p = gp & (NPI - 1);
  const float* fu = fused + (size_t)b * 144 * NPI + p;
  const float* dp = dw + (size_t)b * 126 * NPI + p;
  float g1v[18];
#pragma unroll
  for (int i = 0; i < 18; ++i) g1v[i] = fu[i * NPI] * dp[i * NPI];
  int j0 = wv * 9;
#pragma unroll 1
  for (int jj = 0; jj < 9; ++jj) {
    int j = j0 + jj;
    const float* wp = w + j * 18;
    float s = bias[j];
#pragma unroll
    for (int i = 0; i < 18; ++i) s += wp[i] * g1v[i];
    s *= dp[(18 + j) * NPI];
    g2[((size_t)b * 36 + j) * NPI + p] = s;
  }
}

// ---------- K6: g3 = (pw2 g2 + b)*d2 ----------
__global__ __launch_bounds__(256) void k_g2(const float* __restrict__ g2in,
                                            const float* __restrict__ dw,
                                            const float* __restrict__ w,
                                            const float* __restrict__ bias,
                                            float* __restrict__ g3) {
  int t = threadIdx.x, lane = t & 63;
  int wv = __builtin_amdgcn_readfirstlane(t >> 6);
  int gp = blockIdx.x * 64 + lane;
  int b = gp >> 14, p = gp & (NPI - 1);
  const float* ip = g2in + (size_t)b * 36 * NPI + p;
  const float* dp = dw + (size_t)b * 126 * NPI + p;
  float g[36];
#pragma unroll
  for (int i = 0; i < 36; ++i) g[i] = ip[i * NPI];
  int j0 = wv * 18;
#pragma unroll 1
  for (int jj = 0; jj < 18; ++jj) {
    int j = j0 + jj;
    const float* wp = w + j * 36;
    float s = bias[j];
#pragma unroll
    for (int i = 0; i < 36; ++i) s += wp[i] * g[i];
    s *= dp[(54 + j) * NPI];
    g3[((size_t)b * 72 + j) * NPI + p] = s;
  }
}

// ---------- K7: gout = pout g3 + b ----------
__global__ __launch_bounds__(256) void k_g3(const float* __restrict__ g3in,
                                            const float* __restrict__ w,
                                            const float* __restrict__ bias,
                                            float* __restrict__ gout) {
  int t = threadIdx.x, lane = t & 63;
  int wv = __builtin_amdgcn_readfirstlane(t >> 6);
  int gp = blockIdx.x * 64 + lane;
  int b = gp >> 14, p = gp & (NPI - 1);
  const float* ip = g3in + (size_t)b * 72 * NPI + p;
  float g[72];
#pragma unroll
  for (int i = 0; i < 72; ++i) g[i] = ip[i * NPI];
  int j0 = wv * 18;
#pragma unroll 1
  for (int jj = 0; jj < 18; ++jj) {
    int j = j0 + jj;
    const float* wp = w + j * 72;
    float s = bias[j];
#pragma unroll
    for (int i = 0; i < 72; ++i) s += wp[i] * g[i];
    gout[((size_t)b * 72 + j) * NPI + p] = s;
  }
}

// ---------- K9: out[b,p,co] = sum_i pre[b,i,p]*proj_w[i,co] + proj_b[co] ----------
__global__ __launch_bounds__(256) void k_proj(const float* __restrict__ pre,
                                              const float* __restrict__ w,
                                              const float* __restrict__ bias,
                                              float* __restrict__ out) {
  int t = threadIdx.x;
  int blk = blockIdx.x;              // 512 blocks, 64 px each
  int b = (blk * 64) >> 14;
  int p0 = (blk * 64) & (NPI - 1);
  const float* pp = pre + (size_t)b * 64 * NPI + p0;
  float wreg[64];
#pragma unroll
  for (int i = 0; i < 64; ++i) wreg[i] = w[i * 256 + t];
  float bs = bias[t];
#pragma unroll 1
  for (int px = 0; px < 64; ++px) {
    float s = bs;
#pragma unroll
    for (int i = 0; i < 64; ++i) s += wreg[i] * pp[i * NPI + px];  // uniform -> s_load
    out[((size_t)(b * NPI + p0 + px)) * 256 + t] = s;
  }
}

extern "C" void kernel_launch(void* const* d_in, const int* in_sizes, int n_in,
                              void* d_out, int out_size, void* d_ws, size_t ws_size,
                              hipStream_t stream) {
  const float* x        = (const float*)d_in[0];
  const float* qkv_w    = (const float*)d_in[1];
  const float* qkv_b    = (const float*)d_in[2];
  const float* dc1_dw_w = (const float*)d_in[3];
  const float* dc1_dw_b = (const float*)d_in[4];
  const float* dc1_pw_w = (const float*)d_in[5];
  const float* dc1_pw_b = (const float*)d_in[6];
  const float* dc2_dw_w = (const float*)d_in[7];
  const float* dc2_dw_b = (const float*)d_in[8];
  const float* dc2_pw_w = (const float*)d_in[9];
  const float* dc2_pw_b = (const float*)d_in[10];
  const float* rpb      = (const float*)d_in[11];
  const float* pin_w    = (const float*)d_in[12];
  const float* pin_b    = (const float*)d_in[13];
  const float* dw7_w    = (const float*)d_in[14];
  const float* dw7_b    = (const float*)d_in[15];
  const float* dw5_w    = (const float*)d_in[16];
  const float* dw5_b    = (const float*)d_in[17];
  const float* dw3_w    = (const float*)d_in[18];
  const float* dw3_b    = (const float*)d_in[19];
  const float* pw1_w    = (const float*)d_in[20];
  const float* pw1_b    = (const float*)d_in[21];
  const float* pw2_w    = (const float*)d_in[22];
  const float* pw2_b    = (const float*)d_in[23];
  const float* pout_w   = (const float*)d_in[24];
  const float* pout_b   = (const float*)d_in[25];
  const float* proj_w   = (const float*)d_in[26];
  const float* proj_b   = (const float*)d_in[27];
  (void)in_sizes; (void)n_in; (void)out_size; (void)ws_size;

  // qkv planar tensor lives in d_out (6.29M floats <= 8.39M), consumed before k_proj writes
  float* fbuf = (float*)d_out;
  float* ws    = (float*)d_ws;
  float* wT    = ws;                   // 10368
  float* attn1 = wT + 10368;           // 2359296
  float* fused = attn1 + 2359296;      // 4718592
  float* dwout = fused + 4718592;      // 4128768
  float* g2b   = dwout + 4128768;      // 1179648
  float* g3b   = g2b + 1179648;        // 2359296
  float* goutb = g3b + 2359296;        // 2359296
  float* pre   = goutb + 2359296;      // 2097152   -> total 19,212,416 floats (76.9 MB)

  hipLaunchKernelGGL(k_wt, dim3(21), dim3(256), 0, stream, dc1_pw_w, dc2_pw_w, wT);
  hipLaunchKernelGGL(k_qkv, dim3(512), dim3(256), 0, stream, x, qkv_w, qkv_b, fbuf);
  hipLaunchKernelGGL((k_dep<0>), dim3(64, 16), dim3(256), 0, stream, fbuf,
                     dc1_dw_w, dc1_dw_b, dc2_dw_w, dc2_dw_b, wT, dc1_pw_b, dc2_pw_b,
                     rpb, (const float*)nullptr, (const float*)nullptr, attn1);
  hipLaunchKernelGGL(k_pin, dim3(512), dim3(256), 0, stream, attn1, pin_w, pin_b, fused);
  hipLaunchKernelGGL(k_dwchain, dim3(64, 126, 2), dim3(256), 0, stream, fused,
                     dw7_w, dw7_b, dw5_w, dw5_b, dw3_w, dw3_b, dwout);
  hipLaunchKernelGGL(k_g1, dim3(512), dim3(256), 0, stream, fused, dwout, pw1_w, pw1_b, g2b);
  hipLaunchKernelGGL(k_g2, dim3(512), dim3(256), 0, stream, g2b, dwout, pw2_w, pw2_b, g3b);
  hipLaunchKernelGGL(k_g3, dim3(512), dim3(256), 0, stream, g3b, pout_w, pout_b, goutb);
  hipLaunchKernelGGL((k_dep<1>), dim3(64, 16), dim3(256), 0, stream, fbuf,
                     dc1_dw_w, dc1_dw_b, dc2_dw_w, dc2_dw_b, wT, dc1_pw_b, dc2_pw_b,
                     rpb, goutb, attn1, pre);
  hipLaunchKernelGGL(k_proj, dim3(512), dim3(256), 0, stream, pre, proj_w, proj_b,
                     (float*)d_out);
}